// Round 3
// baseline (480.410 us; speedup 1.0000x reference)
//
#include <hip/hip_runtime.h>

// rFFT-512, register-resident complex-256 FFT (round-2 core, verified), with
// round-3 memory restructure:
//  - grid-stride persistent waves (2000 blocks, 16 rows/wave exact) with
//    register prefetch of the next row -> steady memory-level parallelism
//  - untangle in block layout: lane l produces k = o+4l..o+4l+3 where
//    o = (-row)&3 aligns the 1028-B row base to 16 B -> dwordx4 stores
//  - nontemporal stores: output never re-read; stop evicting the
//    (almost L3-resident) input
// Uniform untangle: zk = L[swz(k&255)], zm = L[swz((256-k)&255)], t = k/512
// handles k=0 (c=1,s=0 -> z0.x+z0.y, 0) and k=256 (c=-1,s=0 -> z0.x-z0.y, 0)
// with no branches.

#define NFFT 512
#define NH 256
#define NRFFT 257
#define WPB 4          // waves per block

typedef float v4f __attribute__((ext_vector_type(4)));

__device__ __forceinline__ float cosr(float t) { return __builtin_amdgcn_cosf(t); }
__device__ __forceinline__ float sinr(float t) { return __builtin_amdgcn_sinf(t); }

// bijective involution on 0..255 spreading high bits into the bank bits
__device__ __forceinline__ int swz(int n) { return n ^ (n >> 4); }

__device__ __forceinline__ void wave_lds_fence() {
    asm volatile("s_waitcnt lgkmcnt(0)" ::: "memory");
}

__global__ __launch_bounds__(256) void rfft512_kernel(const float* __restrict__ x,
                                                      float* __restrict__ out_re,
                                                      float* __restrict__ out_im,
                                                      int nrows) {
    __shared__ float2 lds[WPB][NH];

    const int lane = threadIdx.x & 63;
    const int wid  = threadIdx.x >> 6;
    float2* L = lds[wid];

    const int stride = gridDim.x * WPB;   // total waves
    int row = blockIdx.x * WPB + wid;
    if (row >= nrows) return;             // wave-uniform

    const float2* xz = reinterpret_cast<const float2*>(x);

    // ---- load first row: cyclic layout, z[n] = (x[2n], x[2n+1]), lane has n = l+64q
    float2 v0, v1, v2, v3;
    {
        const float2* p = xz + (size_t)row * NH;
        v0 = p[lane]; v1 = p[lane + 64]; v2 = p[lane + 128]; v3 = p[lane + 192];
    }

    const float INV256 = 0.00390625f;    // 1/256
    const float INV512 = 0.001953125f;   // 1/512

    for (;;) {
        // ---- prefetch next row early (hides HBM latency under the FFT)
        const int nrow = row + stride;
        const bool have_next = (nrow < nrows);   // wave-uniform
        float2 u0, u1, u2, u3;
        if (have_next) {
            const float2* p = xz + (size_t)nrow * NH;
            u0 = p[lane]; u1 = p[lane + 64]; u2 = p[lane + 128]; u3 = p[lane + 192];
        }

        // ---- stage h=128 (lane-local): pairs (v0,v2) j=l ; (v1,v3) j=l+64
        float w1r, w1i;   // W_256^l, squared for stage h=64 (loop-invariant, LICM hoists)
        {
            const float t = (float)lane * INV256;
            w1r = cosr(t); w1i = -sinr(t);                   // e^{-2pi i l/256}
            float dx = v0.x - v2.x, dy = v0.y - v2.y;
            v0.x += v2.x; v0.y += v2.y;
            v2.x = dx * w1r - dy * w1i; v2.y = dx * w1i + dy * w1r;
            const float ur = w1i, ui = -w1r;                 // W_256^{l+64} = W_256^l * (-i)
            dx = v1.x - v3.x; dy = v1.y - v3.y;
            v1.x += v3.x; v1.y += v3.y;
            v3.x = dx * ur - dy * ui; v3.y = dx * ui + dy * ur;
        }

        // ---- stage h=64 (lane-local): pairs (v0,v1),(v2,v3), twiddle W_128^l
        {
            const float wr = w1r * w1r - w1i * w1i;
            const float wi = 2.0f * w1r * w1i;
            float dx = v0.x - v1.x, dy = v0.y - v1.y;
            v0.x += v1.x; v0.y += v1.y;
            v1.x = dx * wr - dy * wi; v1.y = dx * wi + dy * wr;
            dx = v2.x - v3.x; dy = v2.y - v3.y;
            v2.x += v3.x; v2.y += v3.y;
            v3.x = dx * wr - dy * wi; v3.y = dx * wi + dy * wr;
        }

        // ---- stages h=32..2: cross-lane shfl_xor butterflies
        #pragma unroll
        for (int h = 32; h >= 2; h >>= 1) {
            const float t = (float)(lane & (h - 1)) * (0.5f / (float)h);  // j/(2h) rev
            const float wr = cosr(t), wi = -sinr(t);
            const bool hi = (lane & h) != 0;
            auto bfly = [&](float2& v) {
                const float rx = __shfl_xor(v.x, h);
                const float ry = __shfl_xor(v.y, h);
                const float ux = v.x + rx, uy = v.y + ry;
                const float dx = rx - v.x, dy = ry - v.y;   // a-b on hi lanes
                const float tx = dx * wr - dy * wi;
                const float ty = dx * wi + dy * wr;
                v.x = hi ? tx : ux;
                v.y = hi ? ty : uy;
            };
            bfly(v0); bfly(v1); bfly(v2); bfly(v3);
        }

        // ---- stage h=1: twiddle = 1
        {
            const bool hi = (lane & 1) != 0;
            auto bfly1 = [&](float2& v) {
                const float rx = __shfl_xor(v.x, 1);
                const float ry = __shfl_xor(v.y, 1);
                const float ux = v.x + rx, uy = v.y + ry;
                const float dx = rx - v.x, dy = ry - v.y;
                v.x = hi ? dx : ux;
                v.y = hi ? dy : uy;
            };
            bfly1(v0); bfly1(v1); bfly1(v2); bfly1(v3);
        }

        // ---- scatter to LDS natural order: position p = l+64q holds Z[rev8(p)];
        // rev8(l+64q) = 4*rev6(l) + rev2(q); rev2: 0->0, 1->2, 2->1, 3->3
        {
            const int r6 = (int)(__brev((unsigned)lane) >> 26);
            const int base = 4 * r6;
            L[swz(base + 0)] = v0;
            L[swz(base + 2)] = v1;
            L[swz(base + 1)] = v2;
            L[swz(base + 3)] = v3;
        }
        wave_lds_fence();

        // ---- untangle, block layout, aligned x4 nt stores
        {
            float* orr = out_re + (size_t)row * NRFFT;
            float* oir = out_im + (size_t)row * NRFFT;
            const int o  = (4 - (row & 3)) & 3;   // (257*row + o) % 4 == 0
            const int kb = o + 4 * lane;

            v4f re4, im4;
            #pragma unroll
            for (int j = 0; j < 4; ++j) {
                const int k = kb + j;
                const float2 zk = L[swz(k & 255)];
                const float2 zm = L[swz((256 - k) & 255)];
                const float ze_re = 0.5f * (zk.x + zm.x);
                const float ze_im = 0.5f * (zk.y - zm.y);
                const float zo_re = 0.5f * (zk.y + zm.y);
                const float zo_im = -0.5f * (zk.x - zm.x);
                const float t = (float)k * INV512;
                const float c =  cosr(t);
                const float s = -sinr(t);
                re4[j] = ze_re + c * zo_re - s * zo_im;
                im4[j] = ze_im + c * zo_im + s * zo_re;
            }
            if (kb + 3 <= 256) {           // lanes 0..62 always; lane 63 iff o<=1
                __builtin_nontemporal_store(re4, (v4f*)(orr + kb));
                __builtin_nontemporal_store(im4, (v4f*)(oir + kb));
            } else {                        // lane 63, o>=2: store valid k's only
                #pragma unroll
                for (int j = 0; j < 4; ++j)
                    if (kb + j <= 256) {
                        __builtin_nontemporal_store(re4[j], orr + kb + j);
                        __builtin_nontemporal_store(im4[j], oir + kb + j);
                    }
            }
            // leftovers: o==0 -> k=256 (lane 0); o>=1 -> k = lane for lane < o
            const int ke = (o == 0) ? ((lane == 0) ? 256 : -1)
                                    : ((lane < o) ? lane : -1);
            if (ke >= 0) {
                const float2 zk = L[swz(ke & 255)];
                const float2 zm = L[swz((256 - ke) & 255)];
                const float ze_re = 0.5f * (zk.x + zm.x);
                const float ze_im = 0.5f * (zk.y - zm.y);
                const float zo_re = 0.5f * (zk.y + zm.y);
                const float zo_im = -0.5f * (zk.x - zm.x);
                const float t = (float)ke * INV512;
                const float c =  cosr(t);
                const float s = -sinr(t);
                __builtin_nontemporal_store(ze_re + c * zo_re - s * zo_im, orr + ke);
                __builtin_nontemporal_store(ze_im + c * zo_im + s * zo_re, oir + ke);
            }
        }

        if (!have_next) break;
        v0 = u0; v1 = u1; v2 = u2; v3 = u3;
        row = nrow;
        // next iteration's LDS writes are same-wave in-order after this
        // iteration's reads -> no extra fence needed
    }
}

extern "C" void kernel_launch(void* const* d_in, const int* in_sizes, int n_in,
                              void* d_out, int out_size, void* d_ws, size_t ws_size,
                              hipStream_t stream) {
    const float* x = (const float*)d_in[0];
    // d_in[1]/d_in[2] (m_real/m_imag) unused: twiddles computed analytically.
    float* out = (float*)d_out;
    const int nrows = in_sizes[0] / NFFT;            // 32*4000 = 128000
    float* out_re = out;
    float* out_im = out + (size_t)nrows * NRFFT;     // outputs concatenated flat
    int blocks = (nrows + WPB - 1) / WPB;
    if (blocks > 2000) blocks = 2000;                // 8000 waves, 16 rows each exact
    rfft512_kernel<<<blocks, 256, 0, stream>>>(x, out_re, out_im, nrows);
}

// Round 4
// 427.190 us; speedup vs baseline: 1.1246x; 1.1246x over previous
//
#include <hip/hip_runtime.h>

// rFFT-512, one wave per row. Round 4: round-2 register-resident FFT with the
// cross-lane exchange network moved OFF the DS pipe (theory: rounds 1 and 2
// tied at ~151us because both issued ~72 DS ops/row into the one LDS pipe per
// CU; VALU and HBM floors are lower).
//   xor32 -> v_permlane32_swap_b32 (VALU)   both-halves butterfly
//   xor16 -> v_permlane16_swap_b32 (VALU)   both-halves butterfly
//   xor8  -> DPP row_ror:8 (VALU)           partner butterfly
//   xor4  -> __shfl_xor (ds_swizzle)        partner butterfly (8 DS ops)
//   xor2  -> DPP quad_perm [2,3,0,1] (VALU)
//   xor1  -> DPP quad_perm [1,0,3,2] (VALU)
// DS ops/row: 72 -> 24 (8 swizzle + 8 scatter + 8 untangle gather).
// Everything else (layout, twiddles via hardware v_sin/v_cos in revolutions,
// LDS bit-reversal scatter + rfft untangle, launch config) identical to the
// verified round-2 kernel.

#define NFFT 512
#define NH 256
#define NRFFT 257
#define WPB 4          // waves per block

__device__ __forceinline__ float cosr(float t) { return __builtin_amdgcn_cosf(t); }
__device__ __forceinline__ float sinr(float t) { return __builtin_amdgcn_sinf(t); }

// bijective involution on 0..255 spreading high bits into the bank bits
__device__ __forceinline__ int swz(int n) { return n ^ (n >> 4); }

__device__ __forceinline__ void wave_lds_fence() {
    asm volatile("s_waitcnt lgkmcnt(0)" ::: "memory");
}

// ---- VALU cross-lane exchange primitives -----------------------------------
// permlane32_swap with both operands = v: a[l] = v[l&31] (lo input),
// b[l] = v[l|32] (hi input) -> every lane holds BOTH butterfly inputs.
__device__ __forceinline__ void both32(float v, float& lo, float& hi) {
    float a = v, b = v;
    asm("v_permlane32_swap_b32 %0, %1" : "+v"(a), "+v"(b));
    lo = a; hi = b;
}
// permlane16_swap: a[l] = v[l&~16], b[l] = v[l|16]
__device__ __forceinline__ void both16(float v, float& lo, float& hi) {
    float a = v, b = v;
    asm("v_permlane16_swap_b32 %0, %1" : "+v"(a), "+v"(b));
    lo = a; hi = b;
}
// DPP partner fetches (full rows/banks enabled; all source lanes valid)
__device__ __forceinline__ float dpp_xor8(float v) {   // row_ror:8 == xor 8 in 16-row
    return __int_as_float(__builtin_amdgcn_mov_dpp(__float_as_int(v), 0x128, 0xF, 0xF, true));
}
__device__ __forceinline__ float dpp_xor2(float v) {   // quad_perm [2,3,0,1]
    return __int_as_float(__builtin_amdgcn_mov_dpp(__float_as_int(v), 0x4E, 0xF, 0xF, true));
}
__device__ __forceinline__ float dpp_xor1(float v) {   // quad_perm [1,0,3,2]
    return __int_as_float(__builtin_amdgcn_mov_dpp(__float_as_int(v), 0xB1, 0xF, 0xF, true));
}

__global__ __launch_bounds__(256) void rfft512_kernel(const float* __restrict__ x,
                                                      float* __restrict__ out_re,
                                                      float* __restrict__ out_im,
                                                      int nrows) {
    __shared__ float2 lds[WPB][NH];

    const int lane = threadIdx.x & 63;
    const int wid  = threadIdx.x >> 6;
    const int row  = blockIdx.x * WPB + wid;
    if (row >= nrows) return;   // wave-uniform

    // ---- load row: cyclic layout, z[n] = (x[2n], x[2n+1]), lane has n = l+64q
    const float2* x2 = reinterpret_cast<const float2*>(x + (size_t)row * NFFT);
    float2 v0 = x2[lane];
    float2 v1 = x2[lane + 64];
    float2 v2 = x2[lane + 128];
    float2 v3 = x2[lane + 192];

    // ---- stage h=128 (lane-local): pairs (v0,v2) j=l ; (v1,v3) j=l+64
    float w1r, w1i;   // W_256^l, squared for stage h=64
    {
        const float t = (float)lane * 0.00390625f;       // l/256 rev
        w1r = cosr(t); w1i = -sinr(t);                   // e^{-2pi i l/256}
        float dx = v0.x - v2.x, dy = v0.y - v2.y;
        v0.x += v2.x; v0.y += v2.y;
        v2.x = dx * w1r - dy * w1i; v2.y = dx * w1i + dy * w1r;
        const float ur = w1i, ui = -w1r;                 // W_256^{l+64} = W_256^l * (-i)
        dx = v1.x - v3.x; dy = v1.y - v3.y;
        v1.x += v3.x; v1.y += v3.y;
        v3.x = dx * ur - dy * ui; v3.y = dx * ui + dy * ur;
    }

    // ---- stage h=64 (lane-local): pairs (v0,v1),(v2,v3), twiddle W_128^l
    {
        const float wr = w1r * w1r - w1i * w1i;
        const float wi = 2.0f * w1r * w1i;
        float dx = v0.x - v1.x, dy = v0.y - v1.y;
        v0.x += v1.x; v0.y += v1.y;
        v1.x = dx * wr - dy * wi; v1.y = dx * wi + dy * wr;
        dx = v2.x - v3.x; dy = v2.y - v3.y;
        v2.x += v3.x; v2.y += v3.y;
        v3.x = dx * wr - dy * wi; v3.y = dx * wi + dy * wr;
    }

    // ---- stage h=32: permlane32_swap both-halves butterfly
    {
        const float t = (float)(lane & 31) * (0.5f / 32.0f);
        const float wr = cosr(t), wi = -sinr(t);
        const bool hi = (lane & 32) != 0;
        auto bfly = [&](float2& v) {
            float ax, bx, ay, by;
            both32(v.x, ax, bx);
            both32(v.y, ay, by);
            const float sx = ax + bx, sy = ay + by;
            const float dx = ax - bx, dy = ay - by;
            const float tx = dx * wr - dy * wi;
            const float ty = dx * wi + dy * wr;
            v.x = hi ? tx : sx;
            v.y = hi ? ty : sy;
        };
        bfly(v0); bfly(v1); bfly(v2); bfly(v3);
    }

    // ---- stage h=16: permlane16_swap both-halves butterfly
    {
        const float t = (float)(lane & 15) * (0.5f / 16.0f);
        const float wr = cosr(t), wi = -sinr(t);
        const bool hi = (lane & 16) != 0;
        auto bfly = [&](float2& v) {
            float ax, bx, ay, by;
            both16(v.x, ax, bx);
            both16(v.y, ay, by);
            const float sx = ax + bx, sy = ay + by;
            const float dx = ax - bx, dy = ay - by;
            const float tx = dx * wr - dy * wi;
            const float ty = dx * wi + dy * wr;
            v.x = hi ? tx : sx;
            v.y = hi ? ty : sy;
        };
        bfly(v0); bfly(v1); bfly(v2); bfly(v3);
    }

    // ---- stage h=8: DPP row_ror:8 partner butterfly
    {
        const float t = (float)(lane & 7) * (0.5f / 8.0f);
        const float wr = cosr(t), wi = -sinr(t);
        const bool hi = (lane & 8) != 0;
        auto bfly = [&](float2& v) {
            const float rx = dpp_xor8(v.x);
            const float ry = dpp_xor8(v.y);
            const float ux = v.x + rx, uy = v.y + ry;
            const float dx = rx - v.x, dy = ry - v.y;   // a-b on hi lanes
            const float tx = dx * wr - dy * wi;
            const float ty = dx * wi + dy * wr;
            v.x = hi ? tx : ux;
            v.y = hi ? ty : uy;
        };
        bfly(v0); bfly(v1); bfly(v2); bfly(v3);
    }

    // ---- stage h=4: ds_swizzle partner butterfly (only DS-pipe exchange left)
    {
        const float t = (float)(lane & 3) * (0.5f / 4.0f);
        const float wr = cosr(t), wi = -sinr(t);
        const bool hi = (lane & 4) != 0;
        auto bfly = [&](float2& v) {
            const float rx = __shfl_xor(v.x, 4);
            const float ry = __shfl_xor(v.y, 4);
            const float ux = v.x + rx, uy = v.y + ry;
            const float dx = rx - v.x, dy = ry - v.y;
            const float tx = dx * wr - dy * wi;
            const float ty = dx * wi + dy * wr;
            v.x = hi ? tx : ux;
            v.y = hi ? ty : uy;
        };
        bfly(v0); bfly(v1); bfly(v2); bfly(v3);
    }

    // ---- stage h=2: DPP quad_perm [2,3,0,1]
    {
        const float t = (float)(lane & 1) * 0.25f;   // W_4^{0|1} = 1 | -i
        const float wr = cosr(t), wi = -sinr(t);
        const bool hi = (lane & 2) != 0;
        auto bfly = [&](float2& v) {
            const float rx = dpp_xor2(v.x);
            const float ry = dpp_xor2(v.y);
            const float ux = v.x + rx, uy = v.y + ry;
            const float dx = rx - v.x, dy = ry - v.y;
            const float tx = dx * wr - dy * wi;
            const float ty = dx * wi + dy * wr;
            v.x = hi ? tx : ux;
            v.y = hi ? ty : uy;
        };
        bfly(v0); bfly(v1); bfly(v2); bfly(v3);
    }

    // ---- stage h=1: DPP quad_perm [1,0,3,2], twiddle = 1
    {
        const bool hi = (lane & 1) != 0;
        auto bfly1 = [&](float2& v) {
            const float rx = dpp_xor1(v.x);
            const float ry = dpp_xor1(v.y);
            const float ux = v.x + rx, uy = v.y + ry;
            const float dx = rx - v.x, dy = ry - v.y;
            v.x = hi ? dx : ux;
            v.y = hi ? dy : uy;
        };
        bfly1(v0); bfly1(v1); bfly1(v2); bfly1(v3);
    }

    // ---- scatter to LDS natural order: position p = l+64q holds Z[rev8(p)];
    // rev8(l+64q) = 4*rev6(l) + rev2(q); rev2: 0->0, 1->2, 2->1, 3->3
    {
        const int r6 = (int)(__brev((unsigned)lane) >> 26);
        float2* L = lds[wid];
        const int base = 4 * r6;
        L[swz(base + 0)] = v0;
        L[swz(base + 2)] = v1;
        L[swz(base + 1)] = v2;
        L[swz(base + 3)] = v3;
    }
    wave_lds_fence();

    // ---- untangle packed real FFT and store k = 0..256
    {
        const float2* L = lds[wid];
        const float INV512 = 0.001953125f;  // 1/512
        float* orr = out_re + (size_t)row * NRFFT;
        float* oir = out_im + (size_t)row * NRFFT;
        #pragma unroll
        for (int kk = 0; kk < 4; ++kk) {
            const int k = lane + kk * 64;
            if (k == 0) {
                const float2 z0 = L[swz(0)];
                orr[0]   = z0.x + z0.y;  oir[0]   = 0.0f;
                orr[256] = z0.x - z0.y;  oir[256] = 0.0f;
            } else {
                const float2 zk = L[swz(k)];
                const float2 zm = L[swz(256 - k)];
                const float ze_re = 0.5f * (zk.x + zm.x);
                const float ze_im = 0.5f * (zk.y - zm.y);
                const float zo_re = 0.5f * (zk.y + zm.y);
                const float zo_im = -0.5f * (zk.x - zm.x);
                const float t = (float)k * INV512;
                const float c =  cosr(t);
                const float s = -sinr(t);
                orr[k] = ze_re + c * zo_re - s * zo_im;
                oir[k] = ze_im + c * zo_im + s * zo_re;
            }
        }
    }
}

extern "C" void kernel_launch(void* const* d_in, const int* in_sizes, int n_in,
                              void* d_out, int out_size, void* d_ws, size_t ws_size,
                              hipStream_t stream) {
    const float* x = (const float*)d_in[0];
    // d_in[1]/d_in[2] (m_real/m_imag) unused: twiddles computed analytically.
    float* out = (float*)d_out;
    const int nrows = in_sizes[0] / NFFT;            // 32*4000 = 128000
    float* out_re = out;
    float* out_im = out + (size_t)nrows * NRFFT;     // outputs concatenated flat
    const int blocks = (nrows + WPB - 1) / WPB;      // 32000
    rfft512_kernel<<<blocks, 256, 0, stream>>>(x, out_re, out_im, nrows);
}